// Round 1
// baseline (116.810 us; speedup 1.0000x reference)
//
#include <hip/hip_runtime.h>
#include <math.h>

#define H 1024
#define S 2048
#define B 32

// Kernel 1: v[b,h] = sum_k hidden[b,k] * W[k,h]
// grid: B*8 = 256 blocks, 128 threads. Block handles (b, 128 h-columns).
__global__ void __launch_bounds__(128)
proj_hidden_kernel(const float* __restrict__ hidden,
                   const float* __restrict__ W,
                   float* __restrict__ v) {
    __shared__ float hs[H];
    const int b  = blockIdx.x >> 3;
    const int hc = blockIdx.x & 7;
    const int h  = hc * 128 + threadIdx.x;

    // stage hidden[b,:] in LDS (broadcast reads later -> conflict-free)
    for (int i = threadIdx.x; i < H; i += 128) hs[i] = hidden[b * H + i];
    __syncthreads();

    float acc = 0.f;
#pragma unroll 8
    for (int k = 0; k < H; ++k) {
        acc = fmaf(hs[k], W[(size_t)k * H + h], acc);
    }
    v[b * H + h] = acc;
}

// Kernel 2: scores[b,s] = dot(enc[s,b,:], v[b,:])
// One wave (64 lanes) per (s,b) pair; 4 waves per block.
// Each lane: 4x float4 loads (16 floats) -> fully coalesced 1KB/wave/instr.
__global__ void __launch_bounds__(256)
scores_kernel(const float* __restrict__ enc,
              const float* __restrict__ v,
              float* __restrict__ scores) {
    const int wave = threadIdx.x >> 6;
    const int lane = threadIdx.x & 63;
    const int p = blockIdx.x * 4 + wave;   // p in [0, S*B)
    const int s = p >> 5;                  // consecutive waves: same s, diff b
    const int b = p & 31;                  //   -> contiguous enc rows in memory

    const float4* e4 = reinterpret_cast<const float4*>(enc + ((size_t)s * B + b) * H);
    const float4* v4 = reinterpret_cast<const float4*>(v + (size_t)b * H);

    float acc = 0.f;
#pragma unroll
    for (int j = 0; j < 4; ++j) {
        const float4 e = e4[lane + 64 * j];
        const float4 w = v4[lane + 64 * j];
        acc = fmaf(e.x, w.x, acc);
        acc = fmaf(e.y, w.y, acc);
        acc = fmaf(e.z, w.z, acc);
        acc = fmaf(e.w, w.w, acc);
    }
    // wave-64 reduction
#pragma unroll
    for (int off = 32; off > 0; off >>= 1)
        acc += __shfl_down(acc, off, 64);

    if (lane == 0) scores[(size_t)b * S + s] = acc;
}

// Kernel 3: out[b, s] = softmax over s of scores[b, :]
// One block (256 threads) per b; each thread owns 8 elements.
__global__ void __launch_bounds__(256)
softmax_kernel(const float* __restrict__ scores,
               float* __restrict__ out) {
    const int b    = blockIdx.x;
    const int tid  = threadIdx.x;
    const int wave = tid >> 6;
    const int lane = tid & 63;

    __shared__ float wmax[4];
    __shared__ float wsum[4];

    float x[8];
    float m = -INFINITY;
#pragma unroll
    for (int i = 0; i < 8; ++i) {
        x[i] = scores[(size_t)b * S + tid + i * 256];
        m = fmaxf(m, x[i]);
    }
#pragma unroll
    for (int off = 32; off > 0; off >>= 1)
        m = fmaxf(m, __shfl_down(m, off, 64));
    if (lane == 0) wmax[wave] = m;
    __syncthreads();
    m = fmaxf(fmaxf(wmax[0], wmax[1]), fmaxf(wmax[2], wmax[3]));

    float sum = 0.f;
#pragma unroll
    for (int i = 0; i < 8; ++i) {
        x[i] = __expf(x[i] - m);
        sum += x[i];
    }
#pragma unroll
    for (int off = 32; off > 0; off >>= 1)
        sum += __shfl_down(sum, off, 64);
    if (lane == 0) wsum[wave] = sum;
    __syncthreads();
    sum = (wsum[0] + wsum[1]) + (wsum[2] + wsum[3]);

    const float inv = 1.0f / sum;
#pragma unroll
    for (int i = 0; i < 8; ++i) {
        out[(size_t)b * S + tid + i * 256] = x[i] * inv;
    }
}

extern "C" void kernel_launch(void* const* d_in, const int* in_sizes, int n_in,
                              void* d_out, int out_size, void* d_ws, size_t ws_size,
                              hipStream_t stream) {
    const float* hidden = (const float*)d_in[0];   // (1, B, H)
    const float* enc    = (const float*)d_in[1];   // (S, B, H)
    const float* W      = (const float*)d_in[2];   // (H, H)
    // d_in[3] = bias: constant shift per-b in scores -> cancelled by softmax.

    float* v      = (float*)d_ws;        // B*H floats   (128 KB)
    float* scores = v + (size_t)B * H;   // B*S floats   (256 KB)
    float* out    = (float*)d_out;       // B*S floats

    proj_hidden_kernel<<<B * 8, 128, 0, stream>>>(hidden, W, v);
    scores_kernel<<<(S * B) / 4, 256, 0, stream>>>(enc, v, scores);
    softmax_kernel<<<B, 256, 0, stream>>>(scores, out);
}

// Round 2
// 58.670 us; speedup vs baseline: 1.9910x; 1.9910x over previous
//
#include <hip/hip_runtime.h>
#include <math.h>

#define H 1024
#define S 2048
#define B 32

// Kernel 1: v[b,h] = sum_k hidden[b,k] * W[k,h]
// grid = B*8 = 256 blocks, 512 threads.
// Block = (b, 128 h-columns); threads split K into 4 groups of 256.
__global__ void __launch_bounds__(512)
proj_hidden_kernel(const float* __restrict__ hidden,
                   const float* __restrict__ W,
                   float* __restrict__ v) {
    __shared__ float hs[H];
    __shared__ float part[3][128];
    const int b  = blockIdx.x >> 3;
    const int hc = blockIdx.x & 7;
    const int hl = threadIdx.x & 127;
    const int kg = threadIdx.x >> 7;     // 0..3
    const int h  = hc * 128 + hl;

    for (int i = threadIdx.x; i < H; i += 512) hs[i] = hidden[b * H + i];
    __syncthreads();

    const int k0 = kg * 256;
    const float* Wp = W + (size_t)k0 * H + h;
    float a0 = 0.f, a1 = 0.f, a2 = 0.f, a3 = 0.f;
#pragma unroll 4
    for (int k = 0; k < 256; k += 4) {
        a0 = fmaf(hs[k0 + k + 0], Wp[(size_t)(k + 0) * H], a0);
        a1 = fmaf(hs[k0 + k + 1], Wp[(size_t)(k + 1) * H], a1);
        a2 = fmaf(hs[k0 + k + 2], Wp[(size_t)(k + 2) * H], a2);
        a3 = fmaf(hs[k0 + k + 3], Wp[(size_t)(k + 3) * H], a3);
    }
    float acc = (a0 + a1) + (a2 + a3);

    if (kg > 0) part[kg - 1][hl] = acc;
    __syncthreads();
    if (kg == 0) {
        acc += part[0][hl] + part[1][hl] + part[2][hl];
        v[b * H + h] = acc;
    }
}

// Kernel 2: scores[b,s] = dot(enc[s,b,:], v[b,:])
// grid = S/2 = 1024 blocks, 256 threads. Block handles s0, s0+1 for ALL b.
// Thread (b, k) = (t>>3, t&7): 8 threads per b, each covers 32 float4.
// Each block streams 2 x 128KB contiguous enc; v loaded once per 2 rows.
__global__ void __launch_bounds__(256)
scores_kernel(const float* __restrict__ enc,
              const float* __restrict__ v,
              float* __restrict__ scores) {
    const int s0 = blockIdx.x * 2;
    const int b  = threadIdx.x >> 3;
    const int k  = threadIdx.x & 7;

    const float4* e0 = reinterpret_cast<const float4*>(enc + ((size_t)s0 * B + b) * H);
    const float4* e1 = reinterpret_cast<const float4*>(enc + ((size_t)(s0 + 1) * B + b) * H);
    const float4* vb = reinterpret_cast<const float4*>(v + (size_t)b * H);

    float acc0 = 0.f, acc1 = 0.f;
#pragma unroll 4
    for (int j = 0; j < 32; ++j) {
        const int f = k + 8 * j;
        const float4 w = vb[f];
        const float4 x = e0[f];
        const float4 y = e1[f];
        acc0 = fmaf(x.x, w.x, fmaf(x.y, w.y, fmaf(x.z, w.z, fmaf(x.w, w.w, acc0))));
        acc1 = fmaf(y.x, w.x, fmaf(y.y, w.y, fmaf(y.z, w.z, fmaf(y.w, w.w, acc1))));
    }
    // reduce across the 8 lanes sharing this b (lanes are consecutive)
#pragma unroll
    for (int off = 4; off > 0; off >>= 1) {
        acc0 += __shfl_down(acc0, off, 8);
        acc1 += __shfl_down(acc1, off, 8);
    }
    if (k == 0) {
        scores[(size_t)b * S + s0]     = acc0;
        scores[(size_t)b * S + s0 + 1] = acc1;
    }
}

// Kernel 3: out[b, :] = softmax(scores[b, :]) ; one block per b.
__global__ void __launch_bounds__(256)
softmax_kernel(const float* __restrict__ scores,
               float* __restrict__ out) {
    const int b    = blockIdx.x;
    const int tid  = threadIdx.x;
    const int wave = tid >> 6;
    const int lane = tid & 63;

    __shared__ float wmax[4];
    __shared__ float wsum[4];

    float x[8];
    float m = -INFINITY;
#pragma unroll
    for (int i = 0; i < 8; ++i) {
        x[i] = scores[(size_t)b * S + tid + i * 256];
        m = fmaxf(m, x[i]);
    }
#pragma unroll
    for (int off = 32; off > 0; off >>= 1)
        m = fmaxf(m, __shfl_down(m, off, 64));
    if (lane == 0) wmax[wave] = m;
    __syncthreads();
    m = fmaxf(fmaxf(wmax[0], wmax[1]), fmaxf(wmax[2], wmax[3]));

    float sum = 0.f;
#pragma unroll
    for (int i = 0; i < 8; ++i) {
        x[i] = __expf(x[i] - m);
        sum += x[i];
    }
#pragma unroll
    for (int off = 32; off > 0; off >>= 1)
        sum += __shfl_down(sum, off, 64);
    if (lane == 0) wsum[wave] = sum;
    __syncthreads();
    sum = (wsum[0] + wsum[1]) + (wsum[2] + wsum[3]);

    const float inv = 1.0f / sum;
#pragma unroll
    for (int i = 0; i < 8; ++i) {
        out[(size_t)b * S + tid + i * 256] = x[i] * inv;
    }
}

extern "C" void kernel_launch(void* const* d_in, const int* in_sizes, int n_in,
                              void* d_out, int out_size, void* d_ws, size_t ws_size,
                              hipStream_t stream) {
    const float* hidden = (const float*)d_in[0];   // (1, B, H)
    const float* enc    = (const float*)d_in[1];   // (S, B, H)
    const float* W      = (const float*)d_in[2];   // (H, H)
    // d_in[3] = bias: per-b constant shift in scores -> cancelled by softmax.

    float* v      = (float*)d_ws;        // B*H floats
    float* scores = v + (size_t)B * H;   // B*S floats
    float* out    = (float*)d_out;       // B*S floats

    proj_hidden_kernel<<<B * 8, 512, 0, stream>>>(hidden, W, v);
    scores_kernel<<<S / 2, 256, 0, stream>>>(enc, v, scores);
    softmax_kernel<<<B, 256, 0, stream>>>(scores, out);
}

// Round 3
// 54.583 us; speedup vs baseline: 2.1400x; 1.0749x over previous
//
#include <hip/hip_runtime.h>
#include <math.h>

#define H 1024
#define S 2048
#define B 32

// Kernel 1: v[b,h] = sum_k hidden[b,k] * W[k,h]
// grid 256 = (bg: 16 groups of 2 b) x (hc: 16 chunks of 64 cols)
// 512 threads = (kg = t>>4: 32 k-groups) x (hq = t&15: 16 float4 columns)
// Thread k-set is INTERLEAVED: k = kg + 32*kk  ->  hs broadcast reads hit
// distinct banks (conflict-free) and W row loads stay coalesced.
__global__ void __launch_bounds__(512)
proj_hidden_kernel(const float* __restrict__ hidden,
                   const float* __restrict__ W,
                   float* __restrict__ v) {
    __shared__ float hs[2][H];          // 8 KB
    __shared__ float part[32][2][64];   // 16 KB
    const int hc = blockIdx.x & 15;
    const int bg = blockIdx.x >> 4;
    const int hq = threadIdx.x & 15;
    const int kg = threadIdx.x >> 4;

    for (int i = threadIdx.x; i < 2 * H; i += 512)
        hs[i >> 10][i & 1023] = hidden[(bg * 2 + (i >> 10)) * H + (i & 1023)];
    __syncthreads();

    const int h = hc * 64 + hq * 4;
    float4 a0 = {0.f, 0.f, 0.f, 0.f};
    float4 a1 = {0.f, 0.f, 0.f, 0.f};
#pragma unroll 4
    for (int kk = 0; kk < 32; ++kk) {
        const int k = kg + 32 * kk;
        const float h0 = hs[0][k];
        const float h1 = hs[1][k];
        const float4 w = *reinterpret_cast<const float4*>(W + (size_t)k * H + h);
        a0.x = fmaf(h0, w.x, a0.x); a0.y = fmaf(h0, w.y, a0.y);
        a0.z = fmaf(h0, w.z, a0.z); a0.w = fmaf(h0, w.w, a0.w);
        a1.x = fmaf(h1, w.x, a1.x); a1.y = fmaf(h1, w.y, a1.y);
        a1.z = fmaf(h1, w.z, a1.z); a1.w = fmaf(h1, w.w, a1.w);
    }
    *reinterpret_cast<float4*>(&part[kg][0][hq * 4]) = a0;
    *reinterpret_cast<float4*>(&part[kg][1][hq * 4]) = a1;
    __syncthreads();

    if (threadIdx.x < 128) {
        const int bb = threadIdx.x >> 6;
        const int c  = threadIdx.x & 63;
        float sum = 0.f;
#pragma unroll 8
        for (int g = 0; g < 32; ++g) sum += part[g][bb][c];
        v[(bg * 2 + bb) * H + hc * 64 + c] = sum;
    }
}

// Kernel 2: scores[b,s] = dot(enc[s,b,:], v[b,:])
// grid = S/4 = 512 blocks, 256 threads. Block streams 4 rows (512 KB
// contiguous enc) for ALL b; v read once per 4 rows. Thread (b,k)=(t>>3,t&7).
// Per j: 1 v-load + 4 enc loads -> 20 loads in flight under unroll 4.
__global__ void __launch_bounds__(256)
scores_kernel(const float* __restrict__ enc,
              const float* __restrict__ v,
              float* __restrict__ scores) {
    const int s0 = blockIdx.x * 4;
    const int b  = threadIdx.x >> 3;
    const int k  = threadIdx.x & 7;

    const float4* e0 = reinterpret_cast<const float4*>(enc + ((size_t)(s0 + 0) * B + b) * H);
    const float4* e1 = reinterpret_cast<const float4*>(enc + ((size_t)(s0 + 1) * B + b) * H);
    const float4* e2 = reinterpret_cast<const float4*>(enc + ((size_t)(s0 + 2) * B + b) * H);
    const float4* e3 = reinterpret_cast<const float4*>(enc + ((size_t)(s0 + 3) * B + b) * H);
    const float4* vb = reinterpret_cast<const float4*>(v + (size_t)b * H);

    float a0 = 0.f, a1 = 0.f, a2 = 0.f, a3 = 0.f;
#pragma unroll 4
    for (int j = 0; j < 32; ++j) {
        const int f = k + 8 * j;
        const float4 w = vb[f];
        const float4 x0 = e0[f];
        const float4 x1 = e1[f];
        const float4 x2 = e2[f];
        const float4 x3 = e3[f];
        a0 = fmaf(x0.x, w.x, fmaf(x0.y, w.y, fmaf(x0.z, w.z, fmaf(x0.w, w.w, a0))));
        a1 = fmaf(x1.x, w.x, fmaf(x1.y, w.y, fmaf(x1.z, w.z, fmaf(x1.w, w.w, a1))));
        a2 = fmaf(x2.x, w.x, fmaf(x2.y, w.y, fmaf(x2.z, w.z, fmaf(x2.w, w.w, a2))));
        a3 = fmaf(x3.x, w.x, fmaf(x3.y, w.y, fmaf(x3.z, w.z, fmaf(x3.w, w.w, a3))));
    }
#pragma unroll
    for (int off = 4; off > 0; off >>= 1) {
        a0 += __shfl_down(a0, off, 8);
        a1 += __shfl_down(a1, off, 8);
        a2 += __shfl_down(a2, off, 8);
        a3 += __shfl_down(a3, off, 8);
    }
    if (k == 0) {
        float* sp = scores + (size_t)b * S + s0;
        sp[0] = a0; sp[1] = a1; sp[2] = a2; sp[3] = a3;
    }
}

// Kernel 3: out[b, :] = softmax(scores[b, :]) ; one block per b.
__global__ void __launch_bounds__(256)
softmax_kernel(const float* __restrict__ scores,
               float* __restrict__ out) {
    const int b    = blockIdx.x;
    const int tid  = threadIdx.x;
    const int wave = tid >> 6;
    const int lane = tid & 63;

    __shared__ float wmax[4];
    __shared__ float wsum[4];

    float x[8];
    float m = -INFINITY;
#pragma unroll
    for (int i = 0; i < 8; ++i) {
        x[i] = scores[(size_t)b * S + tid + i * 256];
        m = fmaxf(m, x[i]);
    }
#pragma unroll
    for (int off = 32; off > 0; off >>= 1)
        m = fmaxf(m, __shfl_down(m, off, 64));
    if (lane == 0) wmax[wave] = m;
    __syncthreads();
    m = fmaxf(fmaxf(wmax[0], wmax[1]), fmaxf(wmax[2], wmax[3]));

    float sum = 0.f;
#pragma unroll
    for (int i = 0; i < 8; ++i) {
        x[i] = __expf(x[i] - m);
        sum += x[i];
    }
#pragma unroll
    for (int off = 32; off > 0; off >>= 1)
        sum += __shfl_down(sum, off, 64);
    if (lane == 0) wsum[wave] = sum;
    __syncthreads();
    sum = (wsum[0] + wsum[1]) + (wsum[2] + wsum[3]);

    const float inv = 1.0f / sum;
#pragma unroll
    for (int i = 0; i < 8; ++i) {
        out[(size_t)b * S + tid + i * 256] = x[i] * inv;
    }
}

extern "C" void kernel_launch(void* const* d_in, const int* in_sizes, int n_in,
                              void* d_out, int out_size, void* d_ws, size_t ws_size,
                              hipStream_t stream) {
    const float* hidden = (const float*)d_in[0];   // (1, B, H)
    const float* enc    = (const float*)d_in[1];   // (S, B, H)
    const float* W      = (const float*)d_in[2];   // (H, H)
    // d_in[3] = bias: per-b constant shift in scores -> cancelled by softmax.

    float* v      = (float*)d_ws;        // B*H floats
    float* scores = v + (size_t)B * H;   // B*S floats
    float* out    = (float*)d_out;       // B*S floats

    proj_hidden_kernel<<<256, 512, 0, stream>>>(hidden, W, v);
    scores_kernel<<<S / 4, 256, 0, stream>>>(enc, v, scores);
    softmax_kernel<<<B, 256, 0, stream>>>(scores, out);
}